// Round 1
// baseline (13563.901 us; speedup 1.0000x reference)
//
#include <hip/hip_runtime.h>
#include <stdint.h>

// Problem constants
#define Bsz  64
#define Tsz  512
#define NUsz 256
#define NXsz 1024

// Decomposition: 4 groups x 16 batches; 64 WGs per group, 16 columns each; 256 WGs total.
#define NGRP 4
#define GWG  64
#define MB   16
#define NC   16

typedef __attribute__((ext_vector_type(8))) short  short8;
typedef __attribute__((ext_vector_type(4))) float  float4v;

// Workspace layout (d_ws)
#define FLAGX_OFF   0
#define FLAGFX_OFF  2048
#define XBUF_OFF    4096
#define XBUF_PG     65536                 // per group: 2 parities x 64 slices x 512 B
#define FXBUF_OFF   (XBUF_OFF + NGRP * XBUF_PG)
// total ws use: 4096 + 2*4*65536 = 528384 bytes

__device__ __forceinline__ short f2bf(float f) {
  unsigned x = __float_as_uint(f);
  return (short)((x + 0x7fffu + ((x >> 16) & 1u)) >> 16);  // RNE f32->bf16
}

// Init: reset flags, stage x0 slices (bf16) into parity-0 x broadcast buffer.
__global__ void gru_init(const float* __restrict__ x0, unsigned char* __restrict__ ws) {
  unsigned idx = blockIdx.x * 256u + threadIdx.x;   // grid 256 x 256 = 65536
  unsigned* flagx  = (unsigned*)(ws + FLAGX_OFF);
  unsigned* flagfx = (unsigned*)(ws + FLAGFX_OFF);
  if (idx < 256u)      flagx[idx] = 1u;             // x_0 is available
  else if (idx < 512u) flagfx[idx - 256u] = 0u;
  unsigned g = idx >> 14, rem = idx & 16383u;
  unsigned jj = rem >> 8, b = (rem >> 4) & 15u, k = rem & 15u;
  float v = x0[(g * 16u + b) * NXsz + jj * 16u + k];
  *(short*)(ws + XBUF_OFF + g * XBUF_PG + jj * 512u + b * 32u + k * 2u) = f2bf(v);
}

__launch_bounds__(256, 1)
__global__ void gru_persist(const float* __restrict__ u,  const float* __restrict__ x0,
                            const float* __restrict__ Wz, const float* __restrict__ Uz, const float* __restrict__ bz,
                            const float* __restrict__ Wf, const float* __restrict__ Uf, const float* __restrict__ bfp,
                            const float* __restrict__ Wr, const float* __restrict__ Ur, const float* __restrict__ br,
                            float* __restrict__ out, unsigned char* __restrict__ ws)
{
  // LDS: column slabs of U (k<1024) and W (1024..1280) per gate, [n][k] (B^T) layout, +8 pad.
  __shared__ short Ucol[3 * 16 * 1288];        // 123,648 B
  __shared__ float part[4][2][16][17];         // per-wave partial C tiles (padded)
  __shared__ float xs[16][17];                 // fp32 carried state slice
  __shared__ float zs[16][17];                 // z gate slice

  const int bx  = blockIdx.x;
  const int xcd = bx & 7;                      // heuristic XCD round-robin swizzle
  const int g   = xcd >> 1;                    // group -> XCD pair {2g,2g+1}
  const int j   = ((xcd & 1) << 5) | (bx >> 3);
  const int tid = threadIdx.x;
  const int wv  = tid >> 6;
  const int lane = tid & 63;
  const int q   = lane >> 4;
  const int cl  = lane & 15;
  const int col0 = j * NC;

  // ---- one-time: stage U/W column slabs to LDS (bf16) ----
  {
    const float* Us[3] = {Uz, Uf, Ur};
    const float* Ws[3] = {Wz, Wf, Wr};
    for (int gate = 0; gate < 3; ++gate) {
      short* dst = &Ucol[gate * 20608];
      const float* Ug = Us[gate];
      for (int idx = tid; idx < 16 * 1024; idx += 256) {
        int n = idx & 15, k = idx >> 4;
        dst[n * 1288 + k] = f2bf(Ug[k * NXsz + col0 + n]);
      }
      const float* Wg = Ws[gate];
      for (int idx = tid; idx < 16 * 256; idx += 256) {
        int n = idx & 15, k = idx >> 4;
        dst[n * 1288 + 1024 + k] = f2bf(Wg[k * NXsz + col0 + n]);
      }
    }
    int b = tid >> 4, n = tid & 15;
    xs[b][n] = x0[(g * MB + b) * NXsz + col0 + n];   // fp32 local state
  }
  __syncthreads();

  const float bzv = bz[col0 + cl];
  const float bfv = bfp[col0 + cl];
  const float brv = br[col0 + cl];

  unsigned* flagx  = (unsigned*)(ws + FLAGX_OFF)  + g * GWG;
  unsigned* flagfx = (unsigned*)(ws + FLAGFX_OFF) + g * GWG;
  unsigned char* xb_base  = ws + XBUF_OFF  + g * XBUF_PG;
  unsigned char* fxb_base = ws + FXBUF_OFF + g * XBUF_PG;

  const short* Uz_l = &Ucol[0 * 20608 + cl * 1288 + q * 8];
  const short* Uf_l = &Ucol[1 * 20608 + cl * 1288 + q * 8];
  const short* Ur_l = &Ucol[2 * 20608 + cl * 1288 + q * 8];
  // A-fragment address offset within a 32 KB broadcast buffer:
  // slice = 2c + (q>>1), within slice: row b=cl (32 B), half (q&1)*16
  const unsigned lane_off = (unsigned)(cl * 32 + (q & 1) * 16 + (q >> 1) * 512);

  const long uTN = (long)Tsz * NUsz;
  const float* u_row = u + (long)(g * MB + cl) * uTN;  // A row m = cl

  for (int t = 0; t < Tsz; ++t) {
    const int p = t & 1;
    const unsigned char* xb  = xb_base  + p * 32768;
    unsigned char*       fxb = fxb_base + p * 32768;

    // out[b][t][cols] = x_t  (wave 2; xs stable between s4(prev) and phase-2 update)
    if (wv == 2) {
      #pragma unroll
      for (int r = 0; r < 4; ++r) {
        int row = q * 4 + r;
        out[(long)(g * MB + row) * ((long)Tsz * NXsz) + (long)t * NXsz + col0 + cl] = xs[row][cl];
      }
    }

    // ---- flag-independent work first: u-projection fragments + MFMAs ----
    short8 au[2];
    #pragma unroll
    for (int i = 0; i < 2; ++i) {
      const float* up = u_row + (long)t * NUsz + (wv * 2 + i) * 32 + q * 8;
      float4v u0 = *(const float4v*)up;
      float4v u1 = *(const float4v*)(up + 4);
      short8 s;
      s[0]=f2bf(u0[0]); s[1]=f2bf(u0[1]); s[2]=f2bf(u0[2]); s[3]=f2bf(u0[3]);
      s[4]=f2bf(u1[0]); s[5]=f2bf(u1[1]); s[6]=f2bf(u1[2]); s[7]=f2bf(u1[3]);
      au[i] = s;
    }
    float4v accz = {0.f,0.f,0.f,0.f}, accf = {0.f,0.f,0.f,0.f};
    #pragma unroll
    for (int i = 0; i < 2; ++i) {
      const int ko = 1024 + (wv * 2 + i) * 32;
      accz = __builtin_amdgcn_mfma_f32_16x16x32_bf16(au[i], *(const short8*)(Uz_l + ko), accz, 0, 0, 0);
      accf = __builtin_amdgcn_mfma_f32_16x16x32_bf16(au[i], *(const short8*)(Uf_l + ko), accf, 0, 0, 0);
    }

    // ---- phase 1: wait for full x_t, accumulate x@Uz, x@Uf ----
    {
      const unsigned need = (unsigned)(t + 1);
      while (true) {
        unsigned v = __hip_atomic_load(flagx + lane, __ATOMIC_RELAXED, __HIP_MEMORY_SCOPE_AGENT);
        if (__all((int)(v >= need))) break;
        __builtin_amdgcn_s_sleep(1);
      }
      __builtin_amdgcn_fence(__ATOMIC_ACQUIRE, "agent");
    }
    short8 a[8];
    #pragma unroll
    for (int i = 0; i < 8; ++i)
      a[i] = *(const short8*)(xb + lane_off + (unsigned)(wv * 8 + i) * 1024u);
    #pragma unroll
    for (int i = 0; i < 8; ++i) {
      const int c = wv * 8 + i;
      short8 b0 = *(const short8*)(Uz_l + 32 * c);
      short8 b1 = *(const short8*)(Uf_l + 32 * c);
      accz = __builtin_amdgcn_mfma_f32_16x16x32_bf16(a[i], b0, accz, 0, 0, 0);
      accf = __builtin_amdgcn_mfma_f32_16x16x32_bf16(a[i], b1, accf, 0, 0, 0);
    }
    #pragma unroll
    for (int r = 0; r < 4; ++r) {
      part[wv][0][q * 4 + r][cl] = accz[r];
      part[wv][1][q * 4 + r][cl] = accf[r];
    }
    __syncthreads();  // s1

    if (wv == 0) {            // z gate
      #pragma unroll
      for (int r = 0; r < 4; ++r) {
        int row = q * 4 + r;
        float s = part[0][0][row][cl] + part[1][0][row][cl] + part[2][0][row][cl] + part[3][0][row][cl] + bzv;
        zs[row][cl] = 1.f / (1.f + __expf(-s));
      }
    } else if (wv == 1) {     // f gate -> publish f*x slice
      #pragma unroll
      for (int r = 0; r < 4; ++r) {
        int row = q * 4 + r;
        float s = part[0][1][row][cl] + part[1][1][row][cl] + part[2][1][row][cl] + part[3][1][row][cl] + bfv;
        float f = 1.f / (1.f + __expf(-s));
        *(unsigned short*)(fxb + j * 512 + row * 32 + cl * 2) = (unsigned short)f2bf(f * xs[row][cl]);
      }
      __builtin_amdgcn_fence(__ATOMIC_RELEASE, "agent");
      if (lane == 0)
        __hip_atomic_store(flagfx + j, (unsigned)(t + 1), __ATOMIC_RELAXED, __HIP_MEMORY_SCOPE_AGENT);
    }
    __syncthreads();  // s2

    // ---- phase 2: r = tanh(ar + (f.x)@Ur); x_next; publish x slice ----
    float4v accr = {0.f,0.f,0.f,0.f}, accr2 = {0.f,0.f,0.f,0.f};
    #pragma unroll
    for (int i = 0; i < 2; ++i) {
      const int ko = 1024 + (wv * 2 + i) * 32;
      accr = __builtin_amdgcn_mfma_f32_16x16x32_bf16(au[i], *(const short8*)(Ur_l + ko), accr, 0, 0, 0);
    }
    {
      const unsigned need = (unsigned)(t + 1);
      while (true) {
        unsigned v = __hip_atomic_load(flagfx + lane, __ATOMIC_RELAXED, __HIP_MEMORY_SCOPE_AGENT);
        if (__all((int)(v >= need))) break;
        __builtin_amdgcn_s_sleep(1);
      }
      __builtin_amdgcn_fence(__ATOMIC_ACQUIRE, "agent");
    }
    #pragma unroll
    for (int i = 0; i < 8; ++i)
      a[i] = *(const short8*)(fxb + lane_off + (unsigned)(wv * 8 + i) * 1024u);
    #pragma unroll
    for (int i = 0; i < 8; ++i) {
      short8 b2 = *(const short8*)(Ur_l + 32 * (wv * 8 + i));
      if (i & 1) accr2 = __builtin_amdgcn_mfma_f32_16x16x32_bf16(a[i], b2, accr2, 0, 0, 0);
      else       accr  = __builtin_amdgcn_mfma_f32_16x16x32_bf16(a[i], b2, accr,  0, 0, 0);
    }
    accr += accr2;
    #pragma unroll
    for (int r = 0; r < 4; ++r)
      part[wv][0][q * 4 + r][cl] = accr[r];
    __syncthreads();  // s3

    if (wv == 0) {
      unsigned char* xbn = xb_base + ((t + 1) & 1) * 32768;
      #pragma unroll
      for (int r = 0; r < 4; ++r) {
        int row = q * 4 + r;
        float s = part[0][0][row][cl] + part[1][0][row][cl] + part[2][0][row][cl] + part[3][0][row][cl] + brv;
        s = fminf(fmaxf(s, -15.f), 15.f);
        float e  = __expf(2.f * s);
        float rr = (e - 1.f) / (e + 1.f);            // tanh
        float zv = zs[row][cl], xv = xs[row][cl];
        float xn = zv * xv + (1.f - zv) * rr;
        xs[row][cl] = xn;                             // carry fp32 state
        *(unsigned short*)(xbn + j * 512 + row * 32 + cl * 2) = (unsigned short)f2bf(xn);
      }
      __builtin_amdgcn_fence(__ATOMIC_RELEASE, "agent");
      if (lane == 0)
        __hip_atomic_store(flagx + j, (unsigned)(t + 2), __ATOMIC_RELAXED, __HIP_MEMORY_SCOPE_AGENT);
    }
    __syncthreads();  // s4
  }
}

extern "C" void kernel_launch(void* const* d_in, const int* in_sizes, int n_in,
                              void* d_out, int out_size, void* d_ws, size_t ws_size,
                              hipStream_t stream) {
  (void)in_sizes; (void)n_in; (void)out_size; (void)ws_size;
  const float* u   = (const float*)d_in[0];
  const float* x0  = (const float*)d_in[1];
  const float* Wz  = (const float*)d_in[2];
  const float* Uz  = (const float*)d_in[3];
  const float* bz  = (const float*)d_in[4];
  const float* Wf  = (const float*)d_in[5];
  const float* Uf  = (const float*)d_in[6];
  const float* bfp = (const float*)d_in[7];
  const float* Wr  = (const float*)d_in[8];
  const float* Ur  = (const float*)d_in[9];
  const float* br  = (const float*)d_in[10];
  float* out = (float*)d_out;
  unsigned char* ws = (unsigned char*)d_ws;

  hipLaunchKernelGGL(gru_init, dim3(256), dim3(256), 0, stream, x0, ws);

  void* args[] = { (void*)&u, (void*)&x0, (void*)&Wz, (void*)&Uz, (void*)&bz,
                   (void*)&Wf, (void*)&Uf, (void*)&bfp,
                   (void*)&Wr, (void*)&Ur, (void*)&br, (void*)&out, (void*)&ws };
  hipError_t e = hipLaunchCooperativeKernel((const void*)gru_persist, dim3(256), dim3(256),
                                            args, 0, stream);
  if (e != hipSuccess) {
    // Fallback: plain launch (1 WG/CU by LDS limit; 256 blocks on 256 CUs co-resident)
    hipLaunchKernelGGL(gru_persist, dim3(256), dim3(256), 0, stream,
                       u, x0, Wz, Uz, bz, Wf, Uf, bfp, Wr, Ur, br, out, ws);
  }
}

// Round 2
// 2668.862 us; speedup vs baseline: 5.0823x; 5.0823x over previous
//
#include <hip/hip_runtime.h>
#include <stdint.h>

// Problem constants
#define Bsz  64
#define Tsz  512
#define NUsz 256
#define NXsz 1024

// Decomposition: 4 groups x 16 batches; 64 WGs per group, 16 columns each; 256 WGs total.
#define NGRP 4
#define GWG  64
#define MB   16
#define NC   16

typedef __attribute__((ext_vector_type(8))) short  short8;
typedef __attribute__((ext_vector_type(4))) float  float4v;
typedef unsigned long long ull;

// Workspace layout (d_ws)
#define FLAGX_OFF   0
#define FLAGFX_OFF  2048
#define XBUF_OFF    4096
#define XBUF_PG     65536                 // per group: 2 parities x 64 slices x 512 B
#define FXBUF_OFF   (XBUF_OFF + NGRP * XBUF_PG)
// total ws use: 4096 + 2*4*65536 = 528384 bytes

__device__ __forceinline__ short f2bf(float f) {
  unsigned x = __float_as_uint(f);
  return (short)((x + 0x7fffu + ((x >> 16) & 1u)) >> 16);  // RNE f32->bf16
}

// Init: reset flags, stage x0 slices (bf16) into parity-0 x broadcast buffer.
// Plain stores are fine: end-of-kernel L2 writeback makes them LLC-visible
// before gru_persist's sc1 atomic loads run.
__global__ void gru_init(const float* __restrict__ x0, unsigned char* __restrict__ ws) {
  unsigned idx = blockIdx.x * 256u + threadIdx.x;   // grid 256 x 256 = 65536
  unsigned* flagx  = (unsigned*)(ws + FLAGX_OFF);
  unsigned* flagfx = (unsigned*)(ws + FLAGFX_OFF);
  if (idx < 256u)      flagx[idx] = 1u;             // x_0 is available
  else if (idx < 512u) flagfx[idx - 256u] = 0u;
  unsigned g = idx >> 14, rem = idx & 16383u;
  unsigned jj = rem >> 8, b = (rem >> 4) & 15u, k = rem & 15u;
  float v = x0[(g * 16u + b) * NXsz + jj * 16u + k];
  *(short*)(ws + XBUF_OFF + g * XBUF_PG + jj * 512u + b * 32u + k * 2u) = f2bf(v);
}

__device__ __forceinline__ void wait_flags(const unsigned* f, int lane, unsigned need) {
  while (true) {
    unsigned v = __hip_atomic_load(f + lane, __ATOMIC_RELAXED, __HIP_MEMORY_SCOPE_AGENT);
    if (__all((int)(v >= need))) break;
    __builtin_amdgcn_s_sleep(1);
  }
  // Compiler barrier + waitcnt only (workgroup scope => NO buffer_inv).
  __builtin_amdgcn_fence(__ATOMIC_ACQUIRE, "workgroup");
}

__launch_bounds__(256, 1)
__global__ void gru_persist(const float* __restrict__ u,  const float* __restrict__ x0,
                            const float* __restrict__ Wz, const float* __restrict__ Uz, const float* __restrict__ bz,
                            const float* __restrict__ Wf, const float* __restrict__ Uf, const float* __restrict__ bfp,
                            const float* __restrict__ Wr, const float* __restrict__ Ur, const float* __restrict__ br,
                            float* __restrict__ out, unsigned char* __restrict__ ws)
{
  // LDS: column slabs of U (k<1024) and W (1024..1280) per gate, [n][k] (B^T) layout.
  __shared__ short Ucol[3 * 16 * 1288];        // 123,648 B
  __shared__ float part[4][2][16][17];         // per-wave partial C tiles (padded)
  __shared__ float xs[16][17];                 // fp32 carried state slice
  __shared__ float bz_s[16], bf_s[16], br_s[16];

  const int bx  = blockIdx.x;
  const int xcd = bx & 7;                      // heuristic XCD round-robin swizzle
  const int g   = xcd >> 1;                    // group -> XCD pair {2g,2g+1}
  const int j   = ((xcd & 1) << 5) | (bx >> 3);
  const int tid = threadIdx.x;
  const int wv  = tid >> 6;
  const int lane = tid & 63;
  const int q   = lane >> 4;
  const int cl  = lane & 15;
  const int col0 = j * NC;

  // ---- one-time: stage U/W column slabs to LDS (bf16) ----
  {
    const float* Us[3] = {Uz, Uf, Ur};
    const float* Wsv[3] = {Wz, Wf, Wr};
    for (int gate = 0; gate < 3; ++gate) {
      short* dst = &Ucol[gate * 20608];
      const float* Ug = Us[gate];
      for (int idx = tid; idx < 16 * 1024; idx += 256) {
        int n = idx & 15, k = idx >> 4;
        dst[n * 1288 + k] = f2bf(Ug[k * NXsz + col0 + n]);
      }
      const float* Wg = Wsv[gate];
      for (int idx = tid; idx < 16 * 256; idx += 256) {
        int n = idx & 15, k = idx >> 4;
        dst[n * 1288 + 1024 + k] = f2bf(Wg[k * NXsz + col0 + n]);
      }
    }
    int b = tid >> 4, n = tid & 15;
    xs[b][n] = x0[(g * MB + b) * NXsz + col0 + n];   // fp32 local state
    if (tid < 16) {
      bz_s[tid] = bz[col0 + tid];
      bf_s[tid] = bfp[col0 + tid];
      br_s[tid] = br[col0 + tid];
    }
  }
  __syncthreads();

  unsigned* flagx  = (unsigned*)(ws + FLAGX_OFF)  + g * GWG;
  unsigned* flagfx = (unsigned*)(ws + FLAGFX_OFF) + g * GWG;
  unsigned char* xb_base  = ws + XBUF_OFF  + g * XBUF_PG;
  unsigned char* fxb_base = ws + FXBUF_OFF + g * XBUF_PG;

  const short* Uz_l = &Ucol[0 * 20608 + cl * 1288 + q * 8];
  const short* Uf_l = &Ucol[1 * 20608 + cl * 1288 + q * 8];
  const short* Ur_l = &Ucol[2 * 20608 + cl * 1288 + q * 8];
  // A-fragment address offset within a 32 KB broadcast buffer:
  // chunk c: slice = 2c + (q>>1); within slice: row b=cl (32 B), half (q&1)*16
  const unsigned lane_off = (unsigned)(cl * 32 + (q & 1) * 16 + (q >> 1) * 512);

  // Transposed combine pattern (wave 0 / wave 1): one 8-B packed store per lane.
  const int cb  = lane >> 2;          // batch row 0..15
  const int cc0 = (lane & 3) << 2;    // first of 4 consecutive cols

  const long uTN = (long)Tsz * NUsz;
  const float* u_row = u + (long)(g * MB + cl) * uTN;  // A row m = cl

  float zreg[4] = {0.f, 0.f, 0.f, 0.f};

  for (int t = 0; t < Tsz; ++t) {
    const int p = t & 1;
    const unsigned char* xb  = xb_base  + p * 32768;
    unsigned char*       fxb = fxb_base + p * 32768;

    // out[b][t][cols] = x_t  (wave 2; xs stable between s4(prev) and s4)
    if (wv == 2) {
      #pragma unroll
      for (int r = 0; r < 4; ++r) {
        int row = q * 4 + r;
        out[(long)(g * MB + row) * ((long)Tsz * NXsz) + (long)t * NXsz + col0 + cl] = xs[row][cl];
      }
    }

    // ---- flag-independent work first: u-projection fragments + MFMAs ----
    short8 au[2];
    #pragma unroll
    for (int i = 0; i < 2; ++i) {
      const float* up = u_row + (long)t * NUsz + (wv * 2 + i) * 32 + q * 8;
      float4v u0 = *(const float4v*)up;
      float4v u1 = *(const float4v*)(up + 4);
      short8 s;
      s[0]=f2bf(u0[0]); s[1]=f2bf(u0[1]); s[2]=f2bf(u0[2]); s[3]=f2bf(u0[3]);
      s[4]=f2bf(u1[0]); s[5]=f2bf(u1[1]); s[6]=f2bf(u1[2]); s[7]=f2bf(u1[3]);
      au[i] = s;
    }
    float4v accz = {0.f,0.f,0.f,0.f}, accf = {0.f,0.f,0.f,0.f};
    #pragma unroll
    for (int i = 0; i < 2; ++i) {
      const int ko = 1024 + (wv * 2 + i) * 32;
      accz = __builtin_amdgcn_mfma_f32_16x16x32_bf16(au[i], *(const short8*)(Uz_l + ko), accz, 0, 0, 0);
      accf = __builtin_amdgcn_mfma_f32_16x16x32_bf16(au[i], *(const short8*)(Uf_l + ko), accf, 0, 0, 0);
    }

    // ---- phase 1: wait for full x_t, accumulate x@Uz, x@Uf ----
    wait_flags(flagx, lane, (unsigned)(t + 1));
    {
      ull ax[16];
      #pragma unroll
      for (int i = 0; i < 8; ++i) {
        const ull* pp = (const ull*)(xb + lane_off + (unsigned)((wv * 8 + i) * 1024));
        ax[2*i]   = __hip_atomic_load(pp,     __ATOMIC_RELAXED, __HIP_MEMORY_SCOPE_AGENT);
        ax[2*i+1] = __hip_atomic_load(pp + 1, __ATOMIC_RELAXED, __HIP_MEMORY_SCOPE_AGENT);
      }
      #pragma unroll
      for (int i = 0; i < 8; ++i) {
        union { ull u2[2]; short8 s8; } cv;
        cv.u2[0] = ax[2*i]; cv.u2[1] = ax[2*i+1];
        const int c = wv * 8 + i;
        accz = __builtin_amdgcn_mfma_f32_16x16x32_bf16(cv.s8, *(const short8*)(Uz_l + 32 * c), accz, 0, 0, 0);
        accf = __builtin_amdgcn_mfma_f32_16x16x32_bf16(cv.s8, *(const short8*)(Uf_l + 32 * c), accf, 0, 0, 0);
      }
    }
    #pragma unroll
    for (int r = 0; r < 4; ++r) {
      part[wv][0][q * 4 + r][cl] = accz[r];
      part[wv][1][q * 4 + r][cl] = accf[r];
    }
    __syncthreads();  // s1

    if (wv == 0) {            // z gate -> registers (transposed pattern)
      #pragma unroll
      for (int jj2 = 0; jj2 < 4; ++jj2) {
        int c = cc0 + jj2;
        float s = part[0][0][cb][c] + part[1][0][cb][c] + part[2][0][cb][c] + part[3][0][cb][c] + bz_s[c];
        zreg[jj2] = 1.f / (1.f + __expf(-s));
      }
    } else if (wv == 1) {     // f gate -> publish f*x slice (one 8-B atomic per lane)
      ull pack = 0;
      #pragma unroll
      for (int jj2 = 0; jj2 < 4; ++jj2) {
        int c = cc0 + jj2;
        float s = part[0][1][cb][c] + part[1][1][cb][c] + part[2][1][cb][c] + part[3][1][cb][c] + bf_s[c];
        float f = 1.f / (1.f + __expf(-s));
        unsigned short h = (unsigned short)f2bf(f * xs[cb][c]);
        pack |= (ull)h << (16 * jj2);
      }
      __hip_atomic_store((ull*)(fxb + j * 512 + cb * 32 + cc0 * 2), pack,
                         __ATOMIC_RELAXED, __HIP_MEMORY_SCOPE_AGENT);
      __builtin_amdgcn_fence(__ATOMIC_RELEASE, "workgroup");  // s_waitcnt vmcnt(0), no cache ops
      if (lane == 0)
        __hip_atomic_store(flagfx + j, (unsigned)(t + 1), __ATOMIC_RELAXED, __HIP_MEMORY_SCOPE_AGENT);
    }
    __syncthreads();  // s2

    // ---- phase 2: r = tanh(ar + (f.x)@Ur); x_next; publish x slice ----
    float4v accr = {0.f,0.f,0.f,0.f}, accr2 = {0.f,0.f,0.f,0.f};
    #pragma unroll
    for (int i = 0; i < 2; ++i) {
      const int ko = 1024 + (wv * 2 + i) * 32;
      accr = __builtin_amdgcn_mfma_f32_16x16x32_bf16(au[i], *(const short8*)(Ur_l + ko), accr, 0, 0, 0);
    }
    wait_flags(flagfx, lane, (unsigned)(t + 1));
    {
      ull ax[16];
      #pragma unroll
      for (int i = 0; i < 8; ++i) {
        const ull* pp = (const ull*)(fxb + lane_off + (unsigned)((wv * 8 + i) * 1024));
        ax[2*i]   = __hip_atomic_load(pp,     __ATOMIC_RELAXED, __HIP_MEMORY_SCOPE_AGENT);
        ax[2*i+1] = __hip_atomic_load(pp + 1, __ATOMIC_RELAXED, __HIP_MEMORY_SCOPE_AGENT);
      }
      #pragma unroll
      for (int i = 0; i < 8; ++i) {
        union { ull u2[2]; short8 s8; } cv;
        cv.u2[0] = ax[2*i]; cv.u2[1] = ax[2*i+1];
        short8 b2 = *(const short8*)(Ur_l + 32 * (wv * 8 + i));
        if (i & 1) accr2 = __builtin_amdgcn_mfma_f32_16x16x32_bf16(cv.s8, b2, accr2, 0, 0, 0);
        else       accr  = __builtin_amdgcn_mfma_f32_16x16x32_bf16(cv.s8, b2, accr,  0, 0, 0);
      }
    }
    accr += accr2;
    #pragma unroll
    for (int r = 0; r < 4; ++r)
      part[wv][0][q * 4 + r][cl] = accr[r];
    __syncthreads();  // s3

    if (wv == 0) {            // combine + publish x_{t+1}
      unsigned char* xbn = xb_base + ((t + 1) & 1) * 32768;
      ull pack = 0;
      float xnv[4];
      #pragma unroll
      for (int jj2 = 0; jj2 < 4; ++jj2) {
        int c = cc0 + jj2;
        float s = part[0][0][cb][c] + part[1][0][cb][c] + part[2][0][cb][c] + part[3][0][cb][c] + br_s[c];
        s = fminf(fmaxf(s, -15.f), 15.f);
        float e  = __expf(2.f * s);
        float rr = (e - 1.f) / (e + 1.f);            // tanh
        float xv = xs[cb][c];
        float xn = zreg[jj2] * xv + (1.f - zreg[jj2]) * rr;
        xnv[jj2] = xn;
        pack |= (ull)(unsigned short)f2bf(xn) << (16 * jj2);
      }
      #pragma unroll
      for (int jj2 = 0; jj2 < 4; ++jj2) xs[cb][cc0 + jj2] = xnv[jj2];
      __hip_atomic_store((ull*)(xbn + j * 512 + cb * 32 + cc0 * 2), pack,
                         __ATOMIC_RELAXED, __HIP_MEMORY_SCOPE_AGENT);
      __builtin_amdgcn_fence(__ATOMIC_RELEASE, "workgroup");
      if (lane == 0)
        __hip_atomic_store(flagx + j, (unsigned)(t + 2), __ATOMIC_RELAXED, __HIP_MEMORY_SCOPE_AGENT);
    }
    __syncthreads();  // s4
  }
}

extern "C" void kernel_launch(void* const* d_in, const int* in_sizes, int n_in,
                              void* d_out, int out_size, void* d_ws, size_t ws_size,
                              hipStream_t stream) {
  (void)in_sizes; (void)n_in; (void)out_size; (void)ws_size;
  const float* u   = (const float*)d_in[0];
  const float* x0  = (const float*)d_in[1];
  const float* Wz  = (const float*)d_in[2];
  const float* Uz  = (const float*)d_in[3];
  const float* bz  = (const float*)d_in[4];
  const float* Wf  = (const float*)d_in[5];
  const float* Uf  = (const float*)d_in[6];
  const float* bfp = (const float*)d_in[7];
  const float* Wr  = (const float*)d_in[8];
  const float* Ur  = (const float*)d_in[9];
  const float* br  = (const float*)d_in[10];
  float* out = (float*)d_out;
  unsigned char* ws = (unsigned char*)d_ws;

  hipLaunchKernelGGL(gru_init, dim3(256), dim3(256), 0, stream, x0, ws);

  void* args[] = { (void*)&u, (void*)&x0, (void*)&Wz, (void*)&Uz, (void*)&bz,
                   (void*)&Wf, (void*)&Uf, (void*)&bfp,
                   (void*)&Wr, (void*)&Ur, (void*)&br, (void*)&out, (void*)&ws };
  hipError_t e = hipLaunchCooperativeKernel((const void*)gru_persist, dim3(256), dim3(256),
                                            args, 0, stream);
  if (e != hipSuccess) {
    // Fallback: plain launch (1 WG/CU by LDS limit; 256 blocks co-resident)
    hipLaunchKernelGGL(gru_persist, dim3(256), dim3(256), 0, stream,
                       u, x0, Wz, Uz, bz, Wf, Uf, bfp, Wr, Ur, br, out, ws);
  }
}